// Round 3
// baseline (809.871 us; speedup 1.0000x reference)
//
#include <hip/hip_runtime.h>

// NNOpenSetClassifier — R5: barrier-free, LDS-free pure streaming.
//   frame [8,16384,128] f32, templates [64,16384,128] f32, classes [64] int
// Outputs (concat f32): masked_pred [8,N,21], mask [8,N], ncm [8,N],
//                       min_d [8,N], neigh_classes [8,N]
//
// Rationale: R2 (LDS-heavy) / R3 (reg prefetch) / R4 (gload_lds counted-vmcnt)
// all measured within +-10us total => staging latency was never the limiter;
// the remaining shared structure is the LDS round-trip + per-iter barrier
// lockstep. This version removes BOTH:
//  - lane map (np,b,dq): wave owns 4 DISJOINT pixels x 8 batches. Templates
//    are read straight global->VGPR, each byte by exactly one lane-group
//    (4-way b-broadcast within an instruction, coalescer-merged). No LDS,
//    no ds_write, no __syncthreads anywhere.
//  - latency hiding is pure TLP: 4 free-running waves/SIMD; per-SIMD demand
//    ~27 B/cyc vs 10.25 B/cyc HBM share -> HBM-bound with 2.6x slack.
//  - frame rows in registers (64 VGPR), read once. VGPR ~115 -> 4 blk/CU.
//  - running min/argmin ascending t, strict '<'  == jnp.argmin tie rule.

#define NPIX   16384
#define DDIM   128
#define NT     64
#define NB     8
#define NCAT   21
#define THRESH 230.0f
#define P      16

typedef float4 f4;

__global__ __launch_bounds__(256, 4) void nn_openset_kernel(
    const float* __restrict__ frame,   // [8, 16384, 128]
    const float* __restrict__ tmpl,    // [64, 16384, 128]
    const int*   __restrict__ tcls,    // [64]
    float* __restrict__ out)
{
    const int tid = threadIdx.x;
    const int n0  = blockIdx.x * P;

    // lane = np*16 + b*4 + dq ; wave wv owns pixels n0 + wv*4 + {0..3}
    const int wv = tid >> 6;
    const int ln = tid & 63;
    const int np = ln >> 4;          // 0..3  pixel within wave
    const int b  = (ln >> 2) & 3;    // 0..3  -> batches b and b+4
    const int dq = ln & 3;           // 0..3  d-quarter (32 floats)
    const int n  = n0 + wv * 4 + np;
    const int b0 = b, b1 = b + 4;

    // ---- frame quarter-rows into registers (read once, 64 VGPR) ----
    f4 fr0[8], fr1[8];
    {
        const f4* f0 = (const f4*)(frame + ((size_t)b0 * NPIX + n) * DDIM + dq * 32);
        const f4* f1 = (const f4*)(frame + ((size_t)b1 * NPIX + n) * DDIM + dq * 32);
        #pragma unroll
        for (int j = 0; j < 8; ++j) { fr0[j] = f0[j]; fr1[j] = f1[j]; }
    }

    // ---- template stream: this thread's 32-float slice of each plane ----
    const size_t PLANE4 = (size_t)NPIX * (DDIM / 4);
    const f4* tp = (const f4*)tmpl + (size_t)n * (DDIM / 4) + dq * 8;

    float vmin0 = 3.402823466e38f, vmin1 = 3.402823466e38f;
    int   imin0 = 0, imin1 = 0;

    for (int t = 0; t < NT; ++t) {
        f4 tv[8];
        #pragma unroll
        for (int kq = 0; kq < 8; ++kq) tv[kq] = tp[kq];   // global_load_dwordx4 x8
        tp += PLANE4;

        float a0 = 0.0f, a1 = 0.0f;
        #pragma unroll
        for (int kq = 0; kq < 8; ++kq) {
            const f4 v  = tv[kq];
            const f4 x0 = fr0[kq];
            const f4 x1 = fr1[kq];
            float d;
            d = x0.x - v.x; a0 = fmaf(d, d, a0);
            d = x0.y - v.y; a0 = fmaf(d, d, a0);
            d = x0.z - v.z; a0 = fmaf(d, d, a0);
            d = x0.w - v.w; a0 = fmaf(d, d, a0);
            d = x1.x - v.x; a1 = fmaf(d, d, a1);
            d = x1.y - v.y; a1 = fmaf(d, d, a1);
            d = x1.z - v.z; a1 = fmaf(d, d, a1);
            d = x1.w - v.w; a1 = fmaf(d, d, a1);
        }
        // combine the 4 d-quarters (dq lives in lane bits [1:0])
        a0 += __shfl_xor(a0, 1);  a0 += __shfl_xor(a0, 2);
        a1 += __shfl_xor(a1, 1);  a1 += __shfl_xor(a1, 2);

        // running min/argmin (ascending t, strict '<' => lowest index on ties)
        const bool u0 = a0 < vmin0;
        const bool u1 = a1 < vmin1;
        imin0 = u0 ? t : imin0;  vmin0 = u0 ? a0 : vmin0;
        imin1 = u1 ? t : imin1;  vmin1 = u1 ? a1 : vmin1;
    }

    // ---- epilogue: all 4 dq lanes of a (np,b) group agree; split the writes ----
    const int  cls0 = tcls[imin0];
    const int  cls1 = tcls[imin1];
    const bool m0 = (vmin0 <= THRESH);
    const bool m1 = (vmin1 <= THRESH);

    float* o0 = out;                                  // masked_pred [8,N,21]
    float* o1 = out + (size_t)NB * NPIX * NCAT;       // mask        [8,N]
    float* o2 = o1 + NB * NPIX;                       // ncm         [8,N]
    float* o3 = o2 + NB * NPIX;                       // min_d       [8,N]
    float* o4 = o3 + NB * NPIX;                       // neigh_cls   [8,N]

    const size_t p0 = (size_t)b0 * NPIX + n;
    const size_t p1 = (size_t)b1 * NPIX + n;

    if (dq == 0)      { o1[p0] = m0 ? 1.0f : 0.0f;          o1[p1] = m1 ? 1.0f : 0.0f; }
    else if (dq == 1) { o2[p0] = m0 ? (float)cls0 : 20.0f;  o2[p1] = m1 ? (float)cls1 : 20.0f; }
    else if (dq == 2) { o3[p0] = vmin0;                     o3[p1] = vmin1; }
    else              { o4[p0] = (float)cls0;               o4[p1] = (float)cls1; }

    // one-hot * mask: dq lanes split the 21 columns (6+6+6+3)
    #pragma unroll
    for (int j = 0; j < 6; ++j) {
        const int c = dq * 6 + j;
        if (c < NCAT) {
            o0[p0 * NCAT + c] = (m0 && c == cls0) ? 1.0f : 0.0f;
            o0[p1 * NCAT + c] = (m1 && c == cls1) ? 1.0f : 0.0f;
        }
    }
}

extern "C" void kernel_launch(void* const* d_in, const int* in_sizes, int n_in,
                              void* d_out, int out_size, void* d_ws, size_t ws_size,
                              hipStream_t stream) {
    const float* frame = (const float*)d_in[0];
    const float* tmpl  = (const float*)d_in[1];
    const int*   tcls  = (const int*)d_in[2];
    float* outp = (float*)d_out;
    nn_openset_kernel<<<NPIX / P, 256, 0, stream>>>(frame, tmpl, tcls, outp);
}

// Round 4
// 745.967 us; speedup vs baseline: 1.0857x; 1.0857x over previous
//
#include <hip/hip_runtime.h>

// NNOpenSetClassifier — R6: fully decoupled wave-private streaming.
//   frame [8,16384,128] f32, templates [64,16384,128] f32, classes [64] int
// Outputs (concat f32): masked_pred [8,N,21], mask [8,N], ncm [8,N],
//                       min_d [8,N], neigh_classes [8,N]
//
// Evidence model: dur_us = ~605us fixed harness fill/restore + kernel.
// R2~125 / R3~105 / R4~112 / R5~205 (no-LDS 4x-dup regression) us. The
// remaining structure in R4 is the per-iter __syncthreads lockstep. R6:
//  - wave owns 2 pixels x 8 batches; lane = np(2) x b(4: batches b,b+4)
//    x dq8(8: 16-float d-eighth). All batch duplication served by LDS
//    broadcast (8 lanes/address, free), fixing R5's flaw.
//  - templates staged via global_load_lds into WAVE-PRIVATE 4-buffer ring
//    (1KB/tile = exactly 1 dma16/tile/wave). Readiness = the wave's own
//    counted vmcnt (2 tiles stay in flight). ZERO barriers in the kernel.
//  - 3-bit XOR chunk swizzle applied to BOTH the global source address
//    (stays within 128B segments -> coalescing intact) and the ds_read
//    offset: for fixed kq, 64 lanes = 8 bank-quads x 2 addrs x 4-bcast
//    -> 2 words/bank = conflict-free (m136).
//  - frame in registers (32 VGPR), read once; VGPR ~70 -> 16 waves/CU;
//    in-flight 48KB/CU >> 9.2KB latency-BW product -> HBM-bound by design.

#define NPIX   16384
#define DDIM   128
#define NT     64
#define NB     8
#define NCAT   21
#define THRESH 230.0f

typedef float4 f4;

__device__ __forceinline__ void dma16(const float* g, float* l) {
    __builtin_amdgcn_global_load_lds(
        (const __attribute__((address_space(1))) void*)g,
        (__attribute__((address_space(3))) void*)l,
        16 /*bytes, literal*/, 0, 0);
}

__global__ __launch_bounds__(256, 4) void nn_openset_kernel(
    const float* __restrict__ frame,   // [8, 16384, 128]
    const float* __restrict__ tmpl,    // [64, 16384, 128]
    const int*   __restrict__ tcls,    // [64]
    float* __restrict__ out)
{
    __shared__ __align__(16) float ts[4][4][256];   // [buf][wave][1KB] = 16 KB

    const int tid = threadIdx.x;
    const int wv  = tid >> 6;
    const int ln  = tid & 63;
    // lane = np*32 + b*8 + dq8
    const int np  = ln >> 5;           // 0..1  pixel within wave
    const int b   = (ln >> 3) & 3;     // 0..3  -> batches b and b+4
    const int dq8 = ln & 7;            // 0..7  d-eighth (16 floats)
    const int n   = blockIdx.x * 8 + wv * 2 + np;
    const int b0  = b, b1 = b + 4;

    // ---- frame d-eighths into registers (read once, 32 VGPR) ----
    f4 fr0[4], fr1[4];
    {
        const f4* f0 = (const f4*)(frame + ((size_t)b0 * NPIX + n) * DDIM + dq8 * 16);
        const f4* f1 = (const f4*)(frame + ((size_t)b1 * NPIX + n) * DDIM + dq8 * 16);
        #pragma unroll
        for (int j = 0; j < 4; ++j) { fr0[j] = f0[j]; fr1[j] = f1[j]; }
    }

    // ---- template DMA: lane stages 16B chunk src (inverse-swizzled) ----
    // LDS chunk X holds global chunk (X&~7)|((X&7)^sx), sx=(np_x<<2)|X[4:3].
    const size_t PLANE = (size_t)NPIX * DDIM;
    const int sx  = ((ln >> 5) << 2) | ((ln >> 3) & 3);
    const int src = (ln & ~7) | ((ln & 7) ^ sx);
    const float* gp = tmpl + (size_t)(blockIdx.x * 8 + wv * 2) * DDIM + src * 4;

    // ---- swizzled read offsets (floats), loop-invariant ----
    // chunk' = np*32 + ((dq8*4+kq) ^ s3), s3=(np<<2)|(dq8>>1); matches staging.
    const int s3 = (np << 2) | (dq8 >> 1);
    int roff[4];
    #pragma unroll
    for (int kq = 0; kq < 4; ++kq)
        roff[kq] = np * 128 + (((dq8 * 4 + kq) ^ s3) << 2);

    // ---- prologue: 3 tiles in flight, wave-private, no barrier ever ----
    dma16(gp,             &ts[0][wv][0]);
    dma16(gp + PLANE,     &ts[1][wv][0]);
    dma16(gp + 2 * PLANE, &ts[2][wv][0]);
    gp += 3 * PLANE;
    asm volatile("s_waitcnt vmcnt(2)" ::: "memory");  // frame + tile0 resident

    float vmin0 = 3.402823466e38f, vmin1 = 3.402823466e38f;
    int   imin0 = 0, imin1 = 0;

    for (int t = 0; t < NT; ++t) {
        // issue tile t+3 into this wave's ring slot (t+3)&3 == (t-1)&3;
        // its reads (iter t-1) completed before their data was consumed.
        if (t + 3 < NT) { dma16(gp, &ts[(t + 3) & 3][wv][0]); gp += PLANE; }

        const float* tb = &ts[t & 3][wv][0];
        float a0 = 0.0f, a1 = 0.0f;
        #pragma unroll
        for (int kq = 0; kq < 4; ++kq) {
            const f4 tv = *(const f4*)(tb + roff[kq]);   // bcast x8, conflict-free
            const f4 x0 = fr0[kq];
            const f4 x1 = fr1[kq];
            float d;
            d = x0.x - tv.x; a0 = fmaf(d, d, a0);
            d = x0.y - tv.y; a0 = fmaf(d, d, a0);
            d = x0.z - tv.z; a0 = fmaf(d, d, a0);
            d = x0.w - tv.w; a0 = fmaf(d, d, a0);
            d = x1.x - tv.x; a1 = fmaf(d, d, a1);
            d = x1.y - tv.y; a1 = fmaf(d, d, a1);
            d = x1.z - tv.z; a1 = fmaf(d, d, a1);
            d = x1.w - tv.w; a1 = fmaf(d, d, a1);
        }
        // combine 8 d-eighths (dq8 = lane bits [2:0])
        a0 += __shfl_xor(a0, 1); a0 += __shfl_xor(a0, 2); a0 += __shfl_xor(a0, 4);
        a1 += __shfl_xor(a1, 1); a1 += __shfl_xor(a1, 2); a1 += __shfl_xor(a1, 4);

        // running min/argmin (ascending t, strict '<' => lowest index on ties)
        const bool u0 = a0 < vmin0;
        const bool u1 = a1 < vmin1;
        imin0 = u0 ? t : imin0;  vmin0 = u0 ? a0 : vmin0;
        imin1 = u1 ? t : imin1;  vmin1 = u1 ? a1 : vmin1;

        // counted wait: tile t+1 resident, keep 2 newest in flight. No barrier.
        if (t < NT - 1) {
            if (t < NT - 3)       asm volatile("s_waitcnt vmcnt(2)" ::: "memory");
            else if (t == NT - 3) asm volatile("s_waitcnt vmcnt(1)" ::: "memory");
            else                  asm volatile("s_waitcnt vmcnt(0)" ::: "memory");
        }
    }

    // ---- epilogue: all 8 dq8 lanes of a (np,b) group agree; split writes ----
    const int  cls0 = tcls[imin0];
    const int  cls1 = tcls[imin1];
    const bool m0 = (vmin0 <= THRESH);
    const bool m1 = (vmin1 <= THRESH);

    float* o0 = out;                                  // masked_pred [8,N,21]
    float* o1 = out + (size_t)NB * NPIX * NCAT;       // mask        [8,N]
    float* o2 = o1 + NB * NPIX;                       // ncm         [8,N]
    float* o3 = o2 + NB * NPIX;                       // min_d       [8,N]
    float* o4 = o3 + NB * NPIX;                       // neigh_cls   [8,N]

    const size_t p0 = (size_t)b0 * NPIX + n;
    const size_t p1 = (size_t)b1 * NPIX + n;

    if (dq8 == 0)      { o1[p0] = m0 ? 1.0f : 0.0f;          o1[p1] = m1 ? 1.0f : 0.0f; }
    else if (dq8 == 1) { o2[p0] = m0 ? (float)cls0 : 20.0f;  o2[p1] = m1 ? (float)cls1 : 20.0f; }
    else if (dq8 == 2) { o3[p0] = vmin0;                     o3[p1] = vmin1; }
    else if (dq8 == 3) { o4[p0] = (float)cls0;               o4[p1] = (float)cls1; }

    // one-hot * mask: dq8 lanes split the 21 columns (3 each; c>=21 skipped)
    #pragma unroll
    for (int j = 0; j < 3; ++j) {
        const int c = dq8 * 3 + j;
        if (c < NCAT) {
            o0[p0 * NCAT + c] = (m0 && c == cls0) ? 1.0f : 0.0f;
            o0[p1 * NCAT + c] = (m1 && c == cls1) ? 1.0f : 0.0f;
        }
    }
}

extern "C" void kernel_launch(void* const* d_in, const int* in_sizes, int n_in,
                              void* d_out, int out_size, void* d_ws, size_t ws_size,
                              hipStream_t stream) {
    const float* frame = (const float*)d_in[0];
    const float* tmpl  = (const float*)d_in[1];
    const int*   tcls  = (const int*)d_in[2];
    float* outp = (float*)d_out;
    nn_openset_kernel<<<NPIX / 8, 256, 0, stream>>>(frame, tmpl, tcls, outp);
}